// Round 1
// 148.235 us; speedup vs baseline: 1.0172x; 1.0172x over previous
//
#include <hip/hip_runtime.h>
#include <math.h>

// One thread per batch element.
// Pipeline: closed-form 3x3 symmetric eigenvalues -> unrolled MLP (1->23->23->23->1,
// id-path + sum-path, ReLU between) -> spectral reconstruction via Newton divided
// differences (no eigenvectors needed).
//
// This round: middle layers + final layer switch from v_pk_fma_f32 (4 cyc/wave-inst,
// FP32-pipe-bound) to v_dot2_f32_f16 (full-rate f16 pair-dot with f32 accumulate,
// 2 cyc/wave-inst). Hidden state lives as packed f16x2 c-pairs (48 VGPRs) and each
// output needs only 4 live f32 accumulators, so register pressure drops from ~161
// to ~120 -> __launch_bounds__(256,4) doubles occupancy vs the previous version.

#define MLP_W 23
#define NCP   12   // ceil(23/2) c-pairs, pair 11 is (c=22, zero-pad)

typedef _Float16 h2 __attribute__((ext_vector_type(2)));

// packed f16 middle-layer weights: [layer][o][2*cp + t], t=0: (wi[o,2cp],wi[o,2cp+1]),
// t=1: (ws[o,2cp],ws[o,2cp+1]); c=23 padded with 0.
__device__ h2 g_whalf[2][MLP_W][2 * NCP];
// final layer packed the same way: [2*cp + t]
__device__ h2 g_w3[2 * NCP];

__global__ void svh_prep_kernel(const float* __restrict__ wi1, const float* __restrict__ ws1,
                                const float* __restrict__ wi2, const float* __restrict__ ws2,
                                const float* __restrict__ wi3, const float* __restrict__ ws3) {
    int t = blockIdx.x * blockDim.x + threadIdx.x;
    if (t < 2 * MLP_W * NCP) {
        int layer = t / (MLP_W * NCP);
        int rem   = t % (MLP_W * NCP);
        int o = rem / NCP, cp = rem % NCP;
        const float* wi = layer ? wi2 : wi1;
        const float* ws = layer ? ws2 : ws1;
        int c0 = 2 * cp, c1 = 2 * cp + 1;
        float wia = wi[o * MLP_W + c0], wsa = ws[o * MLP_W + c0];
        float wib = (c1 < MLP_W) ? wi[o * MLP_W + c1] : 0.0f;
        float wsb = (c1 < MLP_W) ? ws[o * MLP_W + c1] : 0.0f;
        g_whalf[layer][o][2 * cp]     = (h2){(_Float16)wia, (_Float16)wib};
        g_whalf[layer][o][2 * cp + 1] = (h2){(_Float16)wsa, (_Float16)wsb};
    }
    if (t < NCP) {
        int c0 = 2 * t, c1 = 2 * t + 1;
        float wia = wi3[c0], wsa = ws3[c0];
        float wib = (c1 < MLP_W) ? wi3[c1] : 0.0f;
        float wsb = (c1 < MLP_W) ? ws3[c1] : 0.0f;
        g_w3[2 * t]     = (h2){(_Float16)wia, (_Float16)wib};
        g_w3[2 * t + 1] = (h2){(_Float16)wsa, (_Float16)wsb};
    }
}

__device__ __forceinline__ float sinv(float d) {
    // guarded inverse: exact-tie eigenvalues give exact-tie MLP outputs, so the
    // 0/0 limit value never affects p(X) on the actual spectrum.
    return (fabsf(d) > 1e-20f) ? (1.0f / d) : 0.0f;
}

__global__ __launch_bounds__(256, 4)
void svh_eig_mlp_kernel(
    const float* __restrict__ x,
    const float* __restrict__ wi0, const float* __restrict__ ws0, const float* __restrict__ bb0,
    const float* __restrict__ bb1, const float* __restrict__ bb2, const float* __restrict__ bb3,
    float* __restrict__ out, int B)
{
    int idx = blockIdx.x * blockDim.x + threadIdx.x;
    if (idx >= B) return;

    const float* xp = x + (size_t)idx * 9;
    float x00 = xp[0], x01 = xp[1], x02 = xp[2];
    float x11 = xp[4], x12 = xp[5], x22 = xp[8];

    // ---- closed-form symmetric 3x3 eigenvalues (trigonometric method) ----
    float q   = (x00 + x11 + x22) * (1.0f / 3.0f);
    float a00 = x00 - q, a11 = x11 - q, a22 = x22 - q;
    float p1  = x01 * x01 + x02 * x02 + x12 * x12;
    float p2  = a00 * a00 + a11 * a11 + a22 * a22 + 2.0f * p1;
    float p   = sqrtf(p2 * (1.0f / 6.0f));
    float ip  = sinv(p);
    float d00 = a00 * ip, d11 = a11 * ip, d22 = a22 * ip;
    float c01 = x01 * ip, c02 = x02 * ip, c12 = x12 * ip;
    float detB = d00 * (d11 * d22 - c12 * c12)
               - c01 * (c01 * d22 - c12 * c02)
               + c02 * (c01 * c12 - d11 * c02);
    float r = 0.5f * detB;
    r = fminf(1.0f, fmaxf(-1.0f, r));
    float phi  = acosf(r) * (1.0f / 3.0f);     // phi in [0, pi/3]
    float cph  = __cosf(phi);
    float sph  = sqrtf(fmaxf(0.0f, 1.0f - cph * cph)); // sin(phi) >= 0
    const float SQ3 = 1.7320508075688772f;
    float lc = q + 2.0f * p * cph;                // largest
    float la = q - p * cph - SQ3 * p * sph;       // smallest
    float lb = q - p * cph + SQ3 * p * sph;       // middle

    // ---- MLP on (la, lb, lc), permutation-equivariant, f16 dot2 form ----
    // Hidden state: per channel (t0, t1, t2, s) packed f16x2 along c-pairs.
    h2 H0[NCP], H1[NCP], H2[NCP], HS[NCP];

    // layer 0 (ic = 1), f32 math, convert outputs to packed f16 pairs
    {
        float S = la + lb + lc;
#pragma unroll
        for (int cp = 0; cp < NCP; ++cp) {
            int oa = 2 * cp;
            float wiA = wi0[oa];
            float uA  = fmaf(ws0[oa], S, bb0[oa]);
            float t0a = fmaxf(0.0f, fmaf(wiA, la, uA));
            float t1a = fmaxf(0.0f, fmaf(wiA, lb, uA));
            float t2a = fmaxf(0.0f, fmaf(wiA, lc, uA));
            float t0b = 0.0f, t1b = 0.0f, t2b = 0.0f;
            if (2 * cp + 1 < MLP_W) {
                int ob = 2 * cp + 1;
                float wiB = wi0[ob];
                float uB  = fmaf(ws0[ob], S, bb0[ob]);
                t0b = fmaxf(0.0f, fmaf(wiB, la, uB));
                t1b = fmaxf(0.0f, fmaf(wiB, lb, uB));
                t2b = fmaxf(0.0f, fmaf(wiB, lc, uB));
            }
            H0[cp] = (h2){(_Float16)t0a, (_Float16)t0b};
            H1[cp] = (h2){(_Float16)t1a, (_Float16)t1b};
            H2[cp] = (h2){(_Float16)t2a, (_Float16)t2b};
            HS[cp] = (h2){(_Float16)(t0a + t1a + t2a), (_Float16)(t0b + t1b + t2b)};
        }
    }

    // middle layers: per output o, 12 c-pair dot2s per channel, f32 accumulate.
    // Weights are wave-uniform compile-time-addressed -> SMEM (s_load), costing no
    // VGPRs; only 4 f32 accumulators live per o.
#pragma unroll
    for (int layer = 0; layer < 2; ++layer) {
        const float* bias = (layer == 0) ? bb1 : bb2;
        h2 N0[NCP], N1[NCP], N2[NCP], NS[NCP];
#pragma unroll
        for (int op = 0; op < NCP; ++op) {
            float y0a, y1a, y2a, sa;
            {
                int o = 2 * op;
                float a0 = 0.0f, a1 = 0.0f, a2 = 0.0f, as = 0.0f;
#pragma unroll
                for (int cp = 0; cp < NCP; ++cp) {
                    h2 wv = g_whalf[layer][o][2 * cp];
                    h2 sv = g_whalf[layer][o][2 * cp + 1];
                    a0 = __builtin_amdgcn_fdot2(wv, H0[cp], a0, false);
                    a1 = __builtin_amdgcn_fdot2(wv, H1[cp], a1, false);
                    a2 = __builtin_amdgcn_fdot2(wv, H2[cp], a2, false);
                    as = __builtin_amdgcn_fdot2(sv, HS[cp], as, false);
                }
                float u = as + bias[o];
                y0a = fmaxf(0.0f, a0 + u);
                y1a = fmaxf(0.0f, a1 + u);
                y2a = fmaxf(0.0f, a2 + u);
                sa  = y0a + y1a + y2a;
            }
            float y0b = 0.0f, y1b = 0.0f, y2b = 0.0f, sb = 0.0f;
            if (2 * op + 1 < MLP_W) {
                int o = 2 * op + 1;
                float a0 = 0.0f, a1 = 0.0f, a2 = 0.0f, as = 0.0f;
#pragma unroll
                for (int cp = 0; cp < NCP; ++cp) {
                    h2 wv = g_whalf[layer][o][2 * cp];
                    h2 sv = g_whalf[layer][o][2 * cp + 1];
                    a0 = __builtin_amdgcn_fdot2(wv, H0[cp], a0, false);
                    a1 = __builtin_amdgcn_fdot2(wv, H1[cp], a1, false);
                    a2 = __builtin_amdgcn_fdot2(wv, H2[cp], a2, false);
                    as = __builtin_amdgcn_fdot2(sv, HS[cp], as, false);
                }
                float u = as + bias[o];
                y0b = fmaxf(0.0f, a0 + u);
                y1b = fmaxf(0.0f, a1 + u);
                y2b = fmaxf(0.0f, a2 + u);
                sb  = y0b + y1b + y2b;
            }
            N0[op] = (h2){(_Float16)y0a, (_Float16)y0b};
            N1[op] = (h2){(_Float16)y1a, (_Float16)y1b};
            N2[op] = (h2){(_Float16)y2a, (_Float16)y2b};
            NS[op] = (h2){(_Float16)sa,  (_Float16)sb};
        }
#pragma unroll
        for (int cp = 0; cp < NCP; ++cp) {
            H0[cp] = N0[cp]; H1[cp] = N1[cp]; H2[cp] = N2[cp]; HS[cp] = NS[cp];
        }
    }

    // layer 3 (oc = 1, no ReLU)
    float eva, evb, evc;
    {
        float a0 = 0.0f, a1 = 0.0f, a2 = 0.0f, as = 0.0f;
#pragma unroll
        for (int cp = 0; cp < NCP; ++cp) {
            h2 wv = g_w3[2 * cp];
            h2 sv = g_w3[2 * cp + 1];
            a0 = __builtin_amdgcn_fdot2(wv, H0[cp], a0, false);
            a1 = __builtin_amdgcn_fdot2(wv, H1[cp], a1, false);
            a2 = __builtin_amdgcn_fdot2(wv, H2[cp], a2, false);
            as = __builtin_amdgcn_fdot2(sv, HS[cp], as, false);
        }
        float b3v = bb3[0];
        eva = a0 + as + b3v;   // value at la
        evb = a1 + as + b3v;   // value at lb
        evc = a2 + as + b3v;   // value at lc
    }

    // ---- spectral reconstruction via Newton divided differences ----
    float g1 = (evb - eva) * sinv(lb - la);
    float g2 = (evc - evb) * sinv(lc - lb);
    float c2 = (g2 - g1) * sinv(lc - la);

    float m100 = x00 - la, m111 = x11 - la, m122 = x22 - la;
    float m200 = x00 - lb, m211 = x11 - lb, m222 = x22 - lb;

    float P00 = m100 * m200 + x01 * x01 + x02 * x02;
    float P01 = m100 * x01 + x01 * m211 + x02 * x12;
    float P02 = m100 * x02 + x01 * x12 + x02 * m222;
    float P11 = x01 * x01 + m111 * m211 + x12 * x12;
    float P12 = x01 * x02 + m111 * x12 + x12 * m222;
    float P22 = x02 * x02 + x12 * x12 + m122 * m222;

    float o00 = fmaf(g1, m100, eva) + c2 * P00;
    float o01 = g1 * x01 + c2 * P01;
    float o02 = g1 * x02 + c2 * P02;
    float o11 = fmaf(g1, m111, eva) + c2 * P11;
    float o12 = g1 * x12 + c2 * P12;
    float o22 = fmaf(g1, m122, eva) + c2 * P22;

    float* op = out + (size_t)idx * 9;
    op[0] = o00; op[1] = o01; op[2] = o02;
    op[3] = o01; op[4] = o11; op[5] = o12;
    op[6] = o02; op[7] = o12; op[8] = o22;
}

extern "C" void kernel_launch(void* const* d_in, const int* in_sizes, int n_in,
                              void* d_out, int out_size, void* d_ws, size_t ws_size,
                              hipStream_t stream) {
    const float* x   = (const float*)d_in[0];
    const float* wi0 = (const float*)d_in[1];
    const float* ws0 = (const float*)d_in[2];
    const float* b0  = (const float*)d_in[3];
    const float* wi1 = (const float*)d_in[4];
    const float* ws1 = (const float*)d_in[5];
    const float* b1  = (const float*)d_in[6];
    const float* wi2 = (const float*)d_in[7];
    const float* ws2 = (const float*)d_in[8];
    const float* b2  = (const float*)d_in[9];
    const float* wi3 = (const float*)d_in[10];
    const float* ws3 = (const float*)d_in[11];
    const float* b3  = (const float*)d_in[12];

    int B = in_sizes[0] / 9;
    float* out = (float*)d_out;

    // repack all dot-layer weights to packed f16 c-pairs
    {
        int n = 2 * MLP_W * NCP;   // 552 work items (layer3 piggybacks on t < NCP)
        dim3 block(256);
        dim3 grid((n + 255) / 256);
        hipLaunchKernelGGL(svh_prep_kernel, grid, block, 0, stream,
                           wi1, ws1, wi2, ws2, wi3, ws3);
    }

    dim3 block(256);
    dim3 grid((B + 255) / 256);
    hipLaunchKernelGGL(svh_eig_mlp_kernel, grid, block, 0, stream,
                       x, wi0, ws0, b0, b1, b2, b3,
                       out, B);
}

// Round 2
// 122.910 us; speedup vs baseline: 1.2268x; 1.2060x over previous
//
#include <hip/hip_runtime.h>
#include <math.h>

// One thread per batch element for eig + layer0 + layer3 + reconstruction.
// Middle layers (23x23, id-path + sum-path) run on the MATRIX pipe:
// each 64-thread block is one self-contained wave; threads stage their
// (t0,t1,t2,s) hidden columns in wave-private LDS (f16, K padded to 32) and the
// wave computes Y = W*H via v_mfma_f32_16x16x32_f16 (4 col-tiles x 4 channels x
// 2 M-tiles = 32 MFMA/layer). Bias+ReLU+channel-sum happen in the f32 fragment
// domain (D: col=lane&15, row=4*(lane>>4)+reg), written back as next layer's B.
// This moves ~8.8k VALU-cyc/wave of MACs onto the idle MFMA pipe (~320 cyc).

#define MLP_W 23
#define NCP   12

typedef _Float16 h2   __attribute__((ext_vector_type(2)));
typedef _Float16 f16x4 __attribute__((ext_vector_type(4)));
typedef _Float16 f16x8 __attribute__((ext_vector_type(8)));
typedef float    f32x4 __attribute__((ext_vector_type(4)));

// A-fragments for the two middle layers, packed per-lane for mfma_f32_16x16x32_f16:
// lane l holds A[row = mt*16 + (l&15)][k = 8*(l>>4) + e], e=0..7, zero-padded past 23.
// [layer][mat: 0=Wi 1=Ws][mtile][lane][4 dwords]
__device__ __attribute__((aligned(16))) h2 g_afrag[2][2][2][64][4];
// final layer packed (wi,ws) c-pairs as before
__device__ h2 g_w3[2 * NCP];

__global__ void svh_prep_kernel(const float* __restrict__ wi1, const float* __restrict__ ws1,
                                const float* __restrict__ wi2, const float* __restrict__ ws2,
                                const float* __restrict__ wi3, const float* __restrict__ ws3) {
    int t = blockIdx.x * blockDim.x + threadIdx.x;
    if (t < 512) {   // one thread per [layer][mat][mtile][lane]
        int lane  = t & 63;
        int mt    = (t >> 6) & 1;
        int mat   = (t >> 7) & 1;
        int layer = (t >> 8) & 1;
        const float* W = layer ? (mat ? ws2 : wi2) : (mat ? ws1 : wi1);
        int row = mt * 16 + (lane & 15);
        int g   = lane >> 4;
#pragma unroll
        for (int dw = 0; dw < 4; ++dw) {
            int k0 = 8 * g + 2 * dw, k1 = k0 + 1;
            float a = (row < MLP_W && k0 < MLP_W) ? W[row * MLP_W + k0] : 0.0f;
            float b = (row < MLP_W && k1 < MLP_W) ? W[row * MLP_W + k1] : 0.0f;
            g_afrag[layer][mat][mt][lane][dw] = (h2){(_Float16)a, (_Float16)b};
        }
    }
    if (t < NCP) {
        int c0 = 2 * t, c1 = 2 * t + 1;
        float wia = wi3[c0], wsa = ws3[c0];
        float wib = (c1 < MLP_W) ? wi3[c1] : 0.0f;
        float wsb = (c1 < MLP_W) ? ws3[c1] : 0.0f;
        g_w3[2 * t]     = (h2){(_Float16)wia, (_Float16)wib};
        g_w3[2 * t + 1] = (h2){(_Float16)wsa, (_Float16)wsb};
    }
}

__device__ __forceinline__ float sinv(float d) {
    return (fabsf(d) > 1e-20f) ? (1.0f / d) : 0.0f;
}

__device__ __forceinline__ f32x4 mm16(f16x8 a, f16x8 b) {
    return __builtin_amdgcn_mfma_f32_16x16x32_f16(a, b, (f32x4){0.f, 0.f, 0.f, 0.f}, 0, 0, 0);
}

// LDS layout (per 1-wave block): 4 channel blocks (t0,t1,t2,s) x 64 cols x 56B.
// Col stores k-rows 0..23 as f16 (48B) + 8B pad (bank spread). Fragment group
// g=3 (k=24..31) reads a shared 16B zero block instead.
#define COL_STRIDE 56
#define CHB   (64 * COL_STRIDE)   // 3584
#define ZOFF  (4 * CHB)           // 14336
#define LDSZ  (ZOFF + 16)         // 14352

__global__ __launch_bounds__(64, 3)
void svh_eig_mlp_kernel(
    const float* __restrict__ x,
    const float* __restrict__ wi0, const float* __restrict__ ws0, const float* __restrict__ bb0,
    const float* __restrict__ bb1, const float* __restrict__ bb2, const float* __restrict__ bb3,
    float* __restrict__ out, int B)
{
    __shared__ alignas(16) unsigned char lds[LDSZ];

    const int lane = threadIdx.x;           // 0..63, one wave per block
    const int g    = lane >> 4;
    int idx  = blockIdx.x * 64 + lane;
    int cidx = (idx < B) ? idx : (B - 1);   // NO early return: cooperative MFMA

    const float* xp = x + (size_t)cidx * 9;
    float x00 = xp[0], x01 = xp[1], x02 = xp[2];
    float x11 = xp[4], x12 = xp[5], x22 = xp[8];

    // zero block for the k=24..31 fragment group
    if (lane < 2) *(f16x4*)(lds + ZOFF + 8 * lane) = (f16x4){0, 0, 0, 0};

    // ---- closed-form symmetric 3x3 eigenvalues (trigonometric method) ----
    float q   = (x00 + x11 + x22) * (1.0f / 3.0f);
    float a00 = x00 - q, a11 = x11 - q, a22 = x22 - q;
    float p1  = x01 * x01 + x02 * x02 + x12 * x12;
    float p2  = a00 * a00 + a11 * a11 + a22 * a22 + 2.0f * p1;
    float p   = sqrtf(p2 * (1.0f / 6.0f));
    float ip  = sinv(p);
    float d00 = a00 * ip, d11 = a11 * ip, d22 = a22 * ip;
    float c01 = x01 * ip, c02 = x02 * ip, c12 = x12 * ip;
    float detB = d00 * (d11 * d22 - c12 * c12)
               - c01 * (c01 * d22 - c12 * c02)
               + c02 * (c01 * c12 - d11 * c02);
    float r = 0.5f * detB;
    r = fminf(1.0f, fmaxf(-1.0f, r));
    float phi  = acosf(r) * (1.0f / 3.0f);
    float cph  = __cosf(phi);
    float sph  = sqrtf(fmaxf(0.0f, 1.0f - cph * cph));
    const float SQ3 = 1.7320508075688772f;
    float lc = q + 2.0f * p * cph;
    float la = q - p * cph - SQ3 * p * sph;
    float lb = q - p * cph + SQ3 * p * sph;

    // ---- A fragments + per-lane bias registers ----
    f16x8 Afr[2][2][2];   // [layer][mat][mtile]
#pragma unroll
    for (int L = 0; L < 2; ++L)
#pragma unroll
        for (int m = 0; m < 2; ++m)
#pragma unroll
            for (int mt = 0; mt < 2; ++mt)
                Afr[L][m][mt] = *(const f16x8*)(&g_afrag[L][m][mt][lane][0]);

    float breg[2][2][4];  // [layer][mtile][reg] -> bias at row mt*16+4g+r (0 past 23)
#pragma unroll
    for (int L = 0; L < 2; ++L) {
        const float* bb = L ? bb2 : bb1;
#pragma unroll
        for (int mt = 0; mt < 2; ++mt)
#pragma unroll
            for (int rr = 0; rr < 4; ++rr) {
                int row = mt * 16 + 4 * g + rr;
                breg[L][mt][rr] = (row < MLP_W) ? bb[row] : 0.0f;
            }
    }

    // ---- layer 0 (ic=1): per-thread, write own column (k-ascending f16) ----
    {
        float S = la + lb + lc;
        const int base = lane * COL_STRIDE;
#pragma unroll
        for (int m = 0; m < 6; ++m) {   // rows 4m..4m+3
            float t0[4], t1[4], t2[4], ts[4];
#pragma unroll
            for (int rr = 0; rr < 4; ++rr) {
                int o = 4 * m + rr;
                if (o < MLP_W) {
                    float wiv = wi0[o];
                    float u   = fmaf(ws0[o], S, bb0[o]);
                    t0[rr] = fmaxf(0.0f, fmaf(wiv, la, u));
                    t1[rr] = fmaxf(0.0f, fmaf(wiv, lb, u));
                    t2[rr] = fmaxf(0.0f, fmaf(wiv, lc, u));
                } else { t0[rr] = t1[rr] = t2[rr] = 0.0f; }
                ts[rr] = t0[rr] + t1[rr] + t2[rr];
            }
            f16x4 v0 = {(_Float16)t0[0], (_Float16)t0[1], (_Float16)t0[2], (_Float16)t0[3]};
            f16x4 v1 = {(_Float16)t1[0], (_Float16)t1[1], (_Float16)t1[2], (_Float16)t1[3]};
            f16x4 v2 = {(_Float16)t2[0], (_Float16)t2[1], (_Float16)t2[2], (_Float16)t2[3]};
            f16x4 vs = {(_Float16)ts[0], (_Float16)ts[1], (_Float16)ts[2], (_Float16)ts[3]};
            *(f16x4*)(lds + 0 * CHB + base + 8 * m) = v0;
            *(f16x4*)(lds + 1 * CHB + base + 8 * m) = v1;
            *(f16x4*)(lds + 2 * CHB + base + 8 * m) = v2;
            *(f16x4*)(lds + 3 * CHB + base + 8 * m) = vs;
        }
    }

    // ---- middle layers on the matrix pipe ----
#pragma unroll
    for (int L = 0; L < 2; ++L) {
        __syncthreads();   // 1-wave block: orders LDS writes -> reads
#pragma unroll
        for (int pp = 0; pp < 4; ++pp) {          // col-tiles (16 cols each)
            const int colb = (16 * pp + (lane & 15)) * COL_STRIDE;
            f16x8 bf[4];
#pragma unroll
            for (int h = 0; h < 4; ++h) {
                int off = (g == 3) ? ZOFF : (h * CHB + colb + g * 16);
                f16x4 lo = *(const f16x4*)(lds + off);
                f16x4 hi = *(const f16x4*)(lds + off + 8);
                bf[h] = __builtin_shufflevector(lo, hi, 0, 1, 2, 3, 4, 5, 6, 7);
            }
            f32x4 a0m0 = mm16(Afr[L][0][0], bf[0]);
            f32x4 a0m1 = mm16(Afr[L][0][1], bf[0]);
            f32x4 a1m0 = mm16(Afr[L][0][0], bf[1]);
            f32x4 a1m1 = mm16(Afr[L][0][1], bf[1]);
            f32x4 a2m0 = mm16(Afr[L][0][0], bf[2]);
            f32x4 a2m1 = mm16(Afr[L][0][1], bf[2]);
            f32x4 asm0 = mm16(Afr[L][1][0], bf[3]);
            f32x4 asm1 = mm16(Afr[L][1][1], bf[3]);

            // epilogue in fragment domain: u = z + bias; y_d = relu(y_t + u); s = sum_d
#pragma unroll
            for (int mt = 0; mt < 2; ++mt) {
                if (mt == 1 && g >= 2) continue;  // rows 24..31 are pad (always 0)
                f32x4 c0 = (mt == 0) ? a0m0 : a0m1;
                f32x4 c1 = (mt == 0) ? a1m0 : a1m1;
                f32x4 c2 = (mt == 0) ? a2m0 : a2m1;
                f32x4 cs = (mt == 0) ? asm0 : asm1;
                float y0[4], y1[4], y2[4], sn[4];
#pragma unroll
                for (int rr = 0; rr < 4; ++rr) {
                    float u  = cs[rr] + breg[L][mt][rr];
                    float v0 = fmaxf(0.0f, c0[rr] + u);
                    float v1 = fmaxf(0.0f, c1[rr] + u);
                    float v2 = fmaxf(0.0f, c2[rr] + u);
                    y0[rr] = v0; y1[rr] = v1; y2[rr] = v2;
                    sn[rr] = v0 + v1 + v2;
                }
                int wb = colb + mt * 32 + 8 * g;  // rows mt*16+4g..+3
                f16x4 w0 = {(_Float16)y0[0], (_Float16)y0[1], (_Float16)y0[2], (_Float16)y0[3]};
                f16x4 w1 = {(_Float16)y1[0], (_Float16)y1[1], (_Float16)y1[2], (_Float16)y1[3]};
                f16x4 w2 = {(_Float16)y2[0], (_Float16)y2[1], (_Float16)y2[2], (_Float16)y2[3]};
                f16x4 w3 = {(_Float16)sn[0], (_Float16)sn[1], (_Float16)sn[2], (_Float16)sn[3]};
                *(f16x4*)(lds + 0 * CHB + wb) = w0;
                *(f16x4*)(lds + 1 * CHB + wb) = w1;
                *(f16x4*)(lds + 2 * CHB + wb) = w2;
                *(f16x4*)(lds + 3 * CHB + wb) = w3;
            }
        }
    }
    __syncthreads();

    // ---- layer 3 (oc=1): per-thread, read own column back, fdot2 ----
    float eva, evb, evc;
    {
        float a0 = 0.f, a1 = 0.f, a2 = 0.f, as = 0.f;
        const int base = lane * COL_STRIDE;
#pragma unroll
        for (int m = 0; m < 6; ++m) {   // rows 4m..4m+3 (row 23 is zero, weight pad zero)
            f16x4 q0 = *(const f16x4*)(lds + 0 * CHB + base + 8 * m);
            f16x4 q1 = *(const f16x4*)(lds + 1 * CHB + base + 8 * m);
            f16x4 q2 = *(const f16x4*)(lds + 2 * CHB + base + 8 * m);
            f16x4 qs = *(const f16x4*)(lds + 3 * CHB + base + 8 * m);
            h2 wia = g_w3[4 * m],     wsa = g_w3[4 * m + 1];
            h2 wib = g_w3[4 * m + 2], wsb = g_w3[4 * m + 3];
            a0 = __builtin_amdgcn_fdot2(wia, __builtin_shufflevector(q0, q0, 0, 1), a0, false);
            a0 = __builtin_amdgcn_fdot2(wib, __builtin_shufflevector(q0, q0, 2, 3), a0, false);
            a1 = __builtin_amdgcn_fdot2(wia, __builtin_shufflevector(q1, q1, 0, 1), a1, false);
            a1 = __builtin_amdgcn_fdot2(wib, __builtin_shufflevector(q1, q1, 2, 3), a1, false);
            a2 = __builtin_amdgcn_fdot2(wia, __builtin_shufflevector(q2, q2, 0, 1), a2, false);
            a2 = __builtin_amdgcn_fdot2(wib, __builtin_shufflevector(q2, q2, 2, 3), a2, false);
            as = __builtin_amdgcn_fdot2(wsa, __builtin_shufflevector(qs, qs, 0, 1), as, false);
            as = __builtin_amdgcn_fdot2(wsb, __builtin_shufflevector(qs, qs, 2, 3), as, false);
        }
        float b3v = bb3[0];
        eva = a0 + as + b3v;
        evb = a1 + as + b3v;
        evc = a2 + as + b3v;
    }

    // ---- spectral reconstruction via Newton divided differences ----
    float g1 = (evb - eva) * sinv(lb - la);
    float g2 = (evc - evb) * sinv(lc - lb);
    float c2 = (g2 - g1) * sinv(lc - la);

    float m100 = x00 - la, m111 = x11 - la, m122 = x22 - la;
    float m200 = x00 - lb, m211 = x11 - lb, m222 = x22 - lb;

    float P00 = m100 * m200 + x01 * x01 + x02 * x02;
    float P01 = m100 * x01 + x01 * m211 + x02 * x12;
    float P02 = m100 * x02 + x01 * x12 + x02 * m222;
    float P11 = x01 * x01 + m111 * m211 + x12 * x12;
    float P12 = x01 * x02 + m111 * x12 + x12 * m222;
    float P22 = x02 * x02 + x12 * x12 + m122 * m222;

    float o00 = fmaf(g1, m100, eva) + c2 * P00;
    float o01 = g1 * x01 + c2 * P01;
    float o02 = g1 * x02 + c2 * P02;
    float o11 = fmaf(g1, m111, eva) + c2 * P11;
    float o12 = g1 * x12 + c2 * P12;
    float o22 = fmaf(g1, m122, eva) + c2 * P22;

    if (idx < B) {
        float* op = out + (size_t)idx * 9;
        op[0] = o00; op[1] = o01; op[2] = o02;
        op[3] = o01; op[4] = o11; op[5] = o12;
        op[6] = o02; op[7] = o12; op[8] = o22;
    }
}

extern "C" void kernel_launch(void* const* d_in, const int* in_sizes, int n_in,
                              void* d_out, int out_size, void* d_ws, size_t ws_size,
                              hipStream_t stream) {
    const float* x   = (const float*)d_in[0];
    const float* wi0 = (const float*)d_in[1];
    const float* ws0 = (const float*)d_in[2];
    const float* b0  = (const float*)d_in[3];
    const float* wi1 = (const float*)d_in[4];
    const float* ws1 = (const float*)d_in[5];
    const float* b1  = (const float*)d_in[6];
    const float* wi2 = (const float*)d_in[7];
    const float* ws2 = (const float*)d_in[8];
    const float* b2  = (const float*)d_in[9];
    const float* wi3 = (const float*)d_in[10];
    const float* ws3 = (const float*)d_in[11];
    const float* b3  = (const float*)d_in[12];

    int B = in_sizes[0] / 9;
    float* out = (float*)d_out;

    {
        dim3 block(256);
        dim3 grid(2);   // 512 threads cover all A-fragment + w3 packing
        hipLaunchKernelGGL(svh_prep_kernel, grid, block, 0, stream,
                           wi1, ws1, wi2, ws2, wi3, ws3);
    }

    dim3 block(64);
    dim3 grid((B + 63) / 64);
    hipLaunchKernelGGL(svh_eig_mlp_kernel, grid, block, 0, stream,
                       x, wi0, ws0, b0, b1, b2, b3,
                       out, B);
}

// Round 4
// 119.643 us; speedup vs baseline: 1.2603x; 1.0273x over previous
//
#include <hip/hip_runtime.h>
#include <math.h>

// One thread per batch element for eig + layer0 + reconstruction.
// Middle layers (23x23, id-path + sum-path) and the final 23->1 layer run on the
// MATRIX pipe. Each 64-thread block is ONE wave and is fully self-contained:
// - threads stage (t0,t1,t2) hidden columns in wave-private LDS (f16, K pad 32)
// - Y = Wi*t_d + Ws*(t0+t1+t2) via v_mfma_f32_16x16x32_f16: per 16-col tile,
//   6 id MFMAs + 2x 3-chained sum MFMAs (sum-path accumulates in the MFMA C
//   operand -> no s-channel in LDS: 3 channels, 10.8KB/block, ~15 blocks/CU)
// - layer 3 is ALSO an MFMA: A3 has row0=wi3, row1=ws3, so one MFMA per channel
//   yields dot(wi3,t_d) and dot(ws3,t_d) for 16 columns; __shfl broadcasts to
//   the owning lane.
// NO __syncthreads anywhere: one-wave blocks; a wave's DS ops execute in order,
// so LDS write->read inside the wave is already ordered (removes 3 full
// vmcnt(0)/lgkmcnt(0) barrier drains from the serial chain).

#define MLP_W 23

typedef _Float16 h2    __attribute__((ext_vector_type(2)));
typedef _Float16 f16x4 __attribute__((ext_vector_type(4)));
typedef _Float16 f16x8 __attribute__((ext_vector_type(8)));
typedef float    f32x4 __attribute__((ext_vector_type(4)));

// A-fragments for the two middle layers, packed per-lane for mfma_f32_16x16x32_f16:
// lane l holds A[row = mt*16 + (l&15)][k = 8*(l>>4) + e], e=0..7, zero past 23.
// [layer][mat: 0=Wi 1=Ws][mtile][lane][4 dwords]
__device__ __attribute__((aligned(16))) h2 g_afrag[2][2][2][64][4];
// layer-3 A-fragment: row 0 = wi3, row 1 = ws3, rows 2..15 zero.
__device__ __attribute__((aligned(16))) h2 g_a3frag[64][4];

__global__ void svh_prep_kernel(const float* __restrict__ wi1, const float* __restrict__ ws1,
                                const float* __restrict__ wi2, const float* __restrict__ ws2,
                                const float* __restrict__ wi3, const float* __restrict__ ws3) {
    int t = blockIdx.x * blockDim.x + threadIdx.x;
    if (t < 512) {   // one thread per [layer][mat][mtile][lane]
        int lane  = t & 63;
        int mt    = (t >> 6) & 1;
        int mat   = (t >> 7) & 1;
        int layer = (t >> 8) & 1;
        const float* W = layer ? (mat ? ws2 : wi2) : (mat ? ws1 : wi1);
        int row = mt * 16 + (lane & 15);
        int g   = lane >> 4;
#pragma unroll
        for (int dw = 0; dw < 4; ++dw) {
            int k0 = 8 * g + 2 * dw, k1 = k0 + 1;
            float a = (row < MLP_W && k0 < MLP_W) ? W[row * MLP_W + k0] : 0.0f;
            float b = (row < MLP_W && k1 < MLP_W) ? W[row * MLP_W + k1] : 0.0f;
            g_afrag[layer][mat][mt][lane][dw] = (h2){(_Float16)a, (_Float16)b};
        }
    }
    if (t < 64) {
        int lane = t;
        int row  = lane & 15;
        int g    = lane >> 4;
#pragma unroll
        for (int dw = 0; dw < 4; ++dw) {
            int k0 = 8 * g + 2 * dw, k1 = k0 + 1;
            float a = 0.0f, b = 0.0f;
            if (row == 0) {
                a = (k0 < MLP_W) ? wi3[k0] : 0.0f;
                b = (k1 < MLP_W) ? wi3[k1] : 0.0f;
            } else if (row == 1) {
                a = (k0 < MLP_W) ? ws3[k0] : 0.0f;
                b = (k1 < MLP_W) ? ws3[k1] : 0.0f;
            }
            g_a3frag[lane][dw] = (h2){(_Float16)a, (_Float16)b};
        }
    }
}

__device__ __forceinline__ float sinv(float d) {
    return (fabsf(d) > 1e-20f) ? (1.0f / d) : 0.0f;
}

__device__ __forceinline__ f32x4 mm16(f16x8 a, f16x8 b) {
    return __builtin_amdgcn_mfma_f32_16x16x32_f16(a, b, (f32x4){0.f, 0.f, 0.f, 0.f}, 0, 0, 0);
}
__device__ __forceinline__ f32x4 mm16a(f16x8 a, f16x8 b, f32x4 c) {
    return __builtin_amdgcn_mfma_f32_16x16x32_f16(a, b, c, 0, 0, 0);
}

// LDS layout (per 1-wave block): 3 channel blocks (t0,t1,t2) x 64 cols x 56B.
// Col stores k-rows 0..23 as f16 (48B) + 8B pad (bank spread; 56/4=14 -> 16
// distinct even banks across a 16-lane group). Fragment group g=3 (k=24..31)
// reads a shared 16B zero block.
#define COL_STRIDE 56
#define CHB   (64 * COL_STRIDE)   // 3584
#define ZOFF  (3 * CHB)           // 10752
#define LDSZ  (ZOFF + 16)         // 10768

__global__ __launch_bounds__(64, 4)
void svh_eig_mlp_kernel(
    const float* __restrict__ x,
    const float* __restrict__ wi0, const float* __restrict__ ws0, const float* __restrict__ bb0,
    const float* __restrict__ bb1, const float* __restrict__ bb2, const float* __restrict__ bb3,
    float* __restrict__ out, int B)
{
    __shared__ alignas(16) unsigned char lds[LDSZ];

    const int lane = threadIdx.x;           // 0..63, one wave per block
    const int g    = lane >> 4;
    const int c16  = lane & 15;
    int idx  = blockIdx.x * 64 + lane;
    int cidx = (idx < B) ? idx : (B - 1);   // NO early return: cooperative MFMA

    const float* xp = x + (size_t)cidx * 9;
    float x00 = xp[0], x01 = xp[1], x02 = xp[2];
    float x11 = xp[4], x12 = xp[5], x22 = xp[8];

    // zero block for the k=24..31 fragment group (same-wave DS => ordered)
    if (lane < 2) *(f16x4*)(lds + ZOFF + 8 * lane) = (f16x4){0, 0, 0, 0};

    // ---- closed-form symmetric 3x3 eigenvalues (trigonometric method) ----
    float q   = (x00 + x11 + x22) * (1.0f / 3.0f);
    float a00 = x00 - q, a11 = x11 - q, a22 = x22 - q;
    float p1  = x01 * x01 + x02 * x02 + x12 * x12;
    float p2  = a00 * a00 + a11 * a11 + a22 * a22 + 2.0f * p1;
    float p   = sqrtf(p2 * (1.0f / 6.0f));
    float ip  = sinv(p);
    float d00 = a00 * ip, d11 = a11 * ip, d22 = a22 * ip;
    float c01 = x01 * ip, c02 = x02 * ip, c12 = x12 * ip;
    float detB = d00 * (d11 * d22 - c12 * c12)
               - c01 * (c01 * d22 - c12 * c02)
               + c02 * (c01 * c12 - d11 * c02);
    float r = 0.5f * detB;
    r = fminf(1.0f, fmaxf(-1.0f, r));
    float phi  = acosf(r) * (1.0f / 3.0f);
    float cph  = __cosf(phi);
    float sph  = sqrtf(fmaxf(0.0f, 1.0f - cph * cph));
    const float SQ3 = 1.7320508075688772f;
    float lc = q + 2.0f * p * cph;
    float la = q - p * cph - SQ3 * p * sph;
    float lb = q - p * cph + SQ3 * p * sph;

    // ---- layer 0 (ic=1): per-thread, write own 3-channel column ----
    {
        float S = la + lb + lc;
        const int base = lane * COL_STRIDE;
#pragma unroll
        for (int m = 0; m < 6; ++m) {   // rows 4m..4m+3 (row 23 pads to 0)
            float t0[4], t1[4], t2[4];
#pragma unroll
            for (int rr = 0; rr < 4; ++rr) {
                int o = 4 * m + rr;
                if (o < MLP_W) {
                    float wiv = wi0[o];
                    float u   = fmaf(ws0[o], S, bb0[o]);
                    t0[rr] = fmaxf(0.0f, fmaf(wiv, la, u));
                    t1[rr] = fmaxf(0.0f, fmaf(wiv, lb, u));
                    t2[rr] = fmaxf(0.0f, fmaf(wiv, lc, u));
                } else { t0[rr] = t1[rr] = t2[rr] = 0.0f; }
            }
            f16x4 v0 = {(_Float16)t0[0], (_Float16)t0[1], (_Float16)t0[2], (_Float16)t0[3]};
            f16x4 v1 = {(_Float16)t1[0], (_Float16)t1[1], (_Float16)t1[2], (_Float16)t1[3]};
            f16x4 v2 = {(_Float16)t2[0], (_Float16)t2[1], (_Float16)t2[2], (_Float16)t2[3]};
            *(f16x4*)(lds + 0 * CHB + base + 8 * m) = v0;
            *(f16x4*)(lds + 1 * CHB + base + 8 * m) = v1;
            *(f16x4*)(lds + 2 * CHB + base + 8 * m) = v2;
        }
    }

    // layer-3 A fragment (4 VGPRs, loop-invariant)
    const f16x8 A3 = *(const f16x8*)(&g_a3frag[lane][0]);

    float eva = 0.0f, evb = 0.0f, evc = 0.0f;

    // ---- middle layers + fused layer 3, all on the matrix pipe ----
#pragma unroll
    for (int L = 0; L < 2; ++L) {
        // per-layer A fragments + biases (scoped to keep pressure low)
        f16x8 WiM0 = *(const f16x8*)(&g_afrag[L][0][0][lane][0]);
        f16x8 WiM1 = *(const f16x8*)(&g_afrag[L][0][1][lane][0]);
        f16x8 WsM0 = *(const f16x8*)(&g_afrag[L][1][0][lane][0]);
        f16x8 WsM1 = *(const f16x8*)(&g_afrag[L][1][1][lane][0]);
        const float* bb = L ? bb2 : bb1;
        float breg[2][4];
#pragma unroll
        for (int mt = 0; mt < 2; ++mt)
#pragma unroll
            for (int rr = 0; rr < 4; ++rr) {
                int row = mt * 16 + 4 * g + rr;
                breg[mt][rr] = (row < MLP_W) ? bb[row] : 0.0f;
            }

#pragma unroll
        for (int pp = 0; pp < 4; ++pp) {          // col-tiles (16 cols each)
            const int colb = (16 * pp + c16) * COL_STRIDE;
            f16x8 bf[3];
#pragma unroll
            for (int h = 0; h < 3; ++h) {
                int off = (g == 3) ? ZOFF : (h * CHB + colb + g * 16);
                f16x4 lo = *(const f16x4*)(lds + off);
                f16x4 hi = *(const f16x4*)(lds + off + 8);
                bf[h] = __builtin_shufflevector(lo, hi, 0, 1, 2, 3, 4, 5, 6, 7);
            }
            // id path: 6 independent MFMAs
            f32x4 c0m0 = mm16(WiM0, bf[0]);
            f32x4 c0m1 = mm16(WiM1, bf[0]);
            f32x4 c1m0 = mm16(WiM0, bf[1]);
            f32x4 c1m1 = mm16(WiM1, bf[1]);
            f32x4 c2m0 = mm16(WiM0, bf[2]);
            f32x4 c2m1 = mm16(WiM1, bf[2]);
            // sum path: Ws*(t0+t1+t2) via chained accumulate (f32, no f16 rounding of s)
            f32x4 sm0 = mm16a(WsM0, bf[2], mm16a(WsM0, bf[1], mm16(WsM0, bf[0])));
            f32x4 sm1 = mm16a(WsM1, bf[2], mm16a(WsM1, bf[1], mm16(WsM1, bf[0])));

            // epilogue: u = s + bias; y_d = relu(c_d + u); write 3 channels back
#pragma unroll
            for (int mt = 0; mt < 2; ++mt) {
                if (mt == 1 && g >= 2) continue;  // rows 24..31 are pad
                f32x4 c0 = (mt == 0) ? c0m0 : c0m1;
                f32x4 c1 = (mt == 0) ? c1m0 : c1m1;
                f32x4 c2 = (mt == 0) ? c2m0 : c2m1;
                f32x4 cs = (mt == 0) ? sm0  : sm1;
                float y0[4], y1[4], y2[4];
#pragma unroll
                for (int rr = 0; rr < 4; ++rr) {
                    float u  = cs[rr] + breg[mt][rr];
                    y0[rr] = fmaxf(0.0f, c0[rr] + u);
                    y1[rr] = fmaxf(0.0f, c1[rr] + u);
                    y2[rr] = fmaxf(0.0f, c2[rr] + u);
                }
                int wb = colb + mt * 32 + 8 * g;  // rows mt*16+4g..+3
                f16x4 w0 = {(_Float16)y0[0], (_Float16)y0[1], (_Float16)y0[2], (_Float16)y0[3]};
                f16x4 w1 = {(_Float16)y1[0], (_Float16)y1[1], (_Float16)y1[2], (_Float16)y1[3]};
                f16x4 w2 = {(_Float16)y2[0], (_Float16)y2[1], (_Float16)y2[2], (_Float16)y2[3]};
                *(f16x4*)(lds + 0 * CHB + wb) = w0;
                *(f16x4*)(lds + 1 * CHB + wb) = w1;
                *(f16x4*)(lds + 2 * CHB + wb) = w2;
            }

            // fused layer 3 (only after the last middle layer): read back this
            // tile's fresh columns (same-wave DS => ordered), one MFMA/channel.
            if (L == 1) {
                f16x8 b2f[3];
#pragma unroll
                for (int h = 0; h < 3; ++h) {
                    int off = (g == 3) ? ZOFF : (h * CHB + colb + g * 16);
                    f16x4 lo = *(const f16x4*)(lds + off);
                    f16x4 hi = *(const f16x4*)(lds + off + 8);
                    b2f[h] = __builtin_shufflevector(lo, hi, 0, 1, 2, 3, 4, 5, 6, 7);
                }
                f32x4 D0 = mm16(A3, b2f[0]);   // row0: dot(wi3,t0); row1: dot(ws3,t0)
                f32x4 D1 = mm16(A3, b2f[1]);
                f32x4 D2 = mm16(A3, b2f[2]);
                // valid at g==0 lanes: reg0 = wi3-dot, reg1 = ws3-dot
                float ssum = D0[1] + D1[1] + D2[1];
                float ea = D0[0] + ssum;
                float eb = D1[0] + ssum;
                float ec = D2[0] + ssum;
                ea = __shfl(ea, c16);          // broadcast from g==0 lane of this col
                eb = __shfl(eb, c16);
                ec = __shfl(ec, c16);
                bool own = (g == pp);          // tile pp holds col == lane for g==pp
                eva = own ? ea : eva;
                evb = own ? eb : evb;
                evc = own ? ec : evc;
            }
        }
    }

    {
        float b3v = bb3[0];
        eva += b3v; evb += b3v; evc += b3v;
    }

    // ---- spectral reconstruction via Newton divided differences ----
    float g1 = (evb - eva) * sinv(lb - la);
    float g2 = (evc - evb) * sinv(lc - lb);
    float c2 = (g2 - g1) * sinv(lc - la);

    float m100 = x00 - la, m111 = x11 - la, m122 = x22 - la;
    float m200 = x00 - lb, m211 = x11 - lb, m222 = x22 - lb;

    float P00 = m100 * m200 + x01 * x01 + x02 * x02;
    float P01 = m100 * x01 + x01 * m211 + x02 * x12;
    float P02 = m100 * x02 + x01 * x12 + x02 * m222;
    float P11 = x01 * x01 + m111 * m211 + x12 * x12;
    float P12 = x01 * x02 + m111 * x12 + x12 * m222;
    float P22 = x02 * x02 + x12 * x12 + m122 * m222;

    float o00 = fmaf(g1, m100, eva) + c2 * P00;
    float o01 = g1 * x01 + c2 * P01;
    float o02 = g1 * x02 + c2 * P02;
    float o11 = fmaf(g1, m111, eva) + c2 * P11;
    float o12 = g1 * x12 + c2 * P12;
    float o22 = fmaf(g1, m122, eva) + c2 * P22;

    if (idx < B) {
        float* op = out + (size_t)idx * 9;
        op[0] = o00; op[1] = o01; op[2] = o02;
        op[3] = o01; op[4] = o11; op[5] = o12;
        op[6] = o02; op[7] = o12; op[8] = o22;
    }
}

extern "C" void kernel_launch(void* const* d_in, const int* in_sizes, int n_in,
                              void* d_out, int out_size, void* d_ws, size_t ws_size,
                              hipStream_t stream) {
    const float* x   = (const float*)d_in[0];
    const float* wi0 = (const float*)d_in[1];
    const float* ws0 = (const float*)d_in[2];
    const float* b0  = (const float*)d_in[3];
    const float* wi1 = (const float*)d_in[4];
    const float* ws1 = (const float*)d_in[5];
    const float* b1  = (const float*)d_in[6];
    const float* wi2 = (const float*)d_in[7];
    const float* ws2 = (const float*)d_in[8];
    const float* b2  = (const float*)d_in[9];
    const float* wi3 = (const float*)d_in[10];
    const float* ws3 = (const float*)d_in[11];
    const float* b3  = (const float*)d_in[12];

    int B = in_sizes[0] / 9;
    float* out = (float*)d_out;

    {
        dim3 block(256);
        dim3 grid(2);   // 512 threads cover afrag; first 64 also pack a3frag
        hipLaunchKernelGGL(svh_prep_kernel, grid, block, 0, stream,
                           wi1, ws1, wi2, ws2, wi3, ws3);
    }

    dim3 block(64);
    dim3 grid((B + 63) / 64);
    hipLaunchKernelGGL(svh_eig_mlp_kernel, grid, block, 0, stream,
                       x, wi0, ws0, b0, b1, b2, b3,
                       out, B);
}

// Round 5
// 116.970 us; speedup vs baseline: 1.2891x; 1.0229x over previous
//
#include <hip/hip_runtime.h>
#include <math.h>

// One thread per batch element for eig + layer0 + reconstruction.
// Middle layers (23x23, id + sum path) and layer 3 run on the MATRIX pipe.
// Each 64-thread block is ONE wave, fully self-contained, no __syncthreads
// (a wave's DS ops execute in order).
//
// This round (issue-count reduction — evidence: +36% occupancy bought only +9%,
// so we are issue-bound, not latency-bound):
// - LDS layout [col][kchunk(16B)][ch]: B-fragment load = ONE ds_read_b128 per
//   channel (was 2x ds_read_b64), 16B-aligned, quad-bank slot (c16+3g+h)%8 ->
//   2-way/16-lane group = conflict-free. 9232 B/block -> 16-17 blocks/CU.
// - Packed-f32 epilogue + layer0 (v_pk_fma_f32 / v_pk_max_f32 via vector
//   elementwise builtins): halves the scalar f32 stream. Bit-identical math.
// - x loaded as 2x dwordx4 + 1 dword.

#define MLP_W 23

typedef _Float16 h2    __attribute__((ext_vector_type(2)));
typedef _Float16 f16x4 __attribute__((ext_vector_type(4)));
typedef _Float16 f16x8 __attribute__((ext_vector_type(8)));
typedef float    f32x4 __attribute__((ext_vector_type(4)));
typedef float    v2f   __attribute__((ext_vector_type(2)));
typedef float    f4a   __attribute__((ext_vector_type(4), aligned(4)));

// A-fragments for the two middle layers (mfma_f32_16x16x32_f16):
// lane l holds A[row = mt*16 + (l&15)][k = 8*(l>>4) + e], e=0..7, zero past 22.
__device__ __attribute__((aligned(16))) h2 g_afrag[2][2][2][64][4];
// layer-3 A-fragment: row 0 = wi3, row 1 = ws3, rows 2..15 zero.
__device__ __attribute__((aligned(16))) h2 g_a3frag[64][4];
// layer-0 weights, zero-padded to 24 for pair loads: [0]=wi, [1]=ws, [2]=b
__device__ __attribute__((aligned(16))) float g_l0[3][24];

__global__ void svh_prep_kernel(const float* __restrict__ wi0, const float* __restrict__ ws0,
                                const float* __restrict__ b0,
                                const float* __restrict__ wi1, const float* __restrict__ ws1,
                                const float* __restrict__ wi2, const float* __restrict__ ws2,
                                const float* __restrict__ wi3, const float* __restrict__ ws3) {
    int t = blockIdx.x * blockDim.x + threadIdx.x;
    if (t < 512) {   // one thread per [layer][mat][mtile][lane]
        int lane  = t & 63;
        int mt    = (t >> 6) & 1;
        int mat   = (t >> 7) & 1;
        int layer = (t >> 8) & 1;
        const float* W = layer ? (mat ? ws2 : wi2) : (mat ? ws1 : wi1);
        int row = mt * 16 + (lane & 15);
        int g   = lane >> 4;
#pragma unroll
        for (int dw = 0; dw < 4; ++dw) {
            int k0 = 8 * g + 2 * dw, k1 = k0 + 1;
            float a = (row < MLP_W && k0 < MLP_W) ? W[row * MLP_W + k0] : 0.0f;
            float b = (row < MLP_W && k1 < MLP_W) ? W[row * MLP_W + k1] : 0.0f;
            g_afrag[layer][mat][mt][lane][dw] = (h2){(_Float16)a, (_Float16)b};
        }
    }
    if (t < 64) {
        int lane = t;
        int row  = lane & 15;
        int g    = lane >> 4;
#pragma unroll
        for (int dw = 0; dw < 4; ++dw) {
            int k0 = 8 * g + 2 * dw, k1 = k0 + 1;
            float a = 0.0f, b = 0.0f;
            if (row == 0) {
                a = (k0 < MLP_W) ? wi3[k0] : 0.0f;
                b = (k1 < MLP_W) ? wi3[k1] : 0.0f;
            } else if (row == 1) {
                a = (k0 < MLP_W) ? ws3[k0] : 0.0f;
                b = (k1 < MLP_W) ? ws3[k1] : 0.0f;
            }
            g_a3frag[lane][dw] = (h2){(_Float16)a, (_Float16)b};
        }
    }
    if (t < 24) {
        g_l0[0][t] = (t < MLP_W) ? wi0[t] : 0.0f;
        g_l0[1][t] = (t < MLP_W) ? ws0[t] : 0.0f;
        g_l0[2][t] = (t < MLP_W) ? b0[t]  : 0.0f;
    }
}

__device__ __forceinline__ float sinv(float d) {
    return (fabsf(d) > 1e-20f) ? (1.0f / d) : 0.0f;
}

__device__ __forceinline__ f32x4 mm16(f16x8 a, f16x8 b) {
    return __builtin_amdgcn_mfma_f32_16x16x32_f16(a, b, (f32x4){0.f, 0.f, 0.f, 0.f}, 0, 0, 0);
}
__device__ __forceinline__ f32x4 mm16a(f16x8 a, f16x8 b, f32x4 c) {
    return __builtin_amdgcn_mfma_f32_16x16x32_f16(a, b, c, 0, 0, 0);
}

// LDS: per column (=lane), 3 k-chunks x 3 channels x 16B, col stride 144
// (16-aligned). chunk g' holds k=8g'..8g'+7 (f16x8) of channel h at
// col*144 + g'*48 + h*16. k=24..31 fragment group reads a 16B zero block.
#define COLB 144
#define ZOFF (64 * COLB)    // 9216
#define LDSZ (ZOFF + 16)    // 9232

__global__ __launch_bounds__(64, 4)
void svh_eig_mlp_kernel(
    const float* __restrict__ x,
    const float* __restrict__ bb1, const float* __restrict__ bb2, const float* __restrict__ bb3,
    float* __restrict__ out, int B)
{
    __shared__ alignas(16) unsigned char lds[LDSZ];

    const int lane = threadIdx.x;           // 0..63, one wave per block
    const int g    = lane >> 4;
    const int c16  = lane & 15;
    int idx  = blockIdx.x * 64 + lane;
    int cidx = (idx < B) ? idx : (B - 1);   // NO early return: cooperative MFMA

    const float* xp = x + (size_t)cidx * 9;
    f4a xa = *(const f4a*)(xp);       // x[0..3]
    f4a xb = *(const f4a*)(xp + 4);   // x[4..7]
    float x22 = xp[8];
    float x00 = xa[0], x01 = xa[1], x02 = xa[2];
    float x11 = xb[0], x12 = xb[1];

    // zero block for the k=24..31 fragment group (same-wave DS => ordered)
    if (lane == 0) *(f32x4*)(lds + ZOFF) = (f32x4){0.f, 0.f, 0.f, 0.f};

    // ---- closed-form symmetric 3x3 eigenvalues (trigonometric method) ----
    float q   = (x00 + x11 + x22) * (1.0f / 3.0f);
    float a00 = x00 - q, a11 = x11 - q, a22 = x22 - q;
    float p1  = x01 * x01 + x02 * x02 + x12 * x12;
    float p2  = a00 * a00 + a11 * a11 + a22 * a22 + 2.0f * p1;
    float p   = sqrtf(p2 * (1.0f / 6.0f));
    float ip  = sinv(p);
    float d00 = a00 * ip, d11 = a11 * ip, d22 = a22 * ip;
    float c01 = x01 * ip, c02 = x02 * ip, c12 = x12 * ip;
    float detB = d00 * (d11 * d22 - c12 * c12)
               - c01 * (c01 * d22 - c12 * c02)
               + c02 * (c01 * c12 - d11 * c02);
    float r = 0.5f * detB;
    r = fminf(1.0f, fmaxf(-1.0f, r));
    float phi  = acosf(r) * (1.0f / 3.0f);
    float cph  = __cosf(phi);
    float sph  = sqrtf(fmaxf(0.0f, 1.0f - cph * cph));
    const float SQ3 = 1.7320508075688772f;
    float lc = q + 2.0f * p * cph;
    float la = q - p * cph - SQ3 * p * sph;
    float lb = q - p * cph + SQ3 * p * sph;

    // ---- layer 0 (ic=1): packed-f32 pairs, write own 3-channel column ----
    {
        float S = la + lb + lc;
        v2f Sv = {S, S}, lav = {la, la}, lbv = {lb, lb}, lcv = {lc, lc};
        v2f z2 = {0.f, 0.f};
        const v2f* L0WI = (const v2f*)g_l0[0];
        const v2f* L0WS = (const v2f*)g_l0[1];
        const v2f* L0BB = (const v2f*)g_l0[2];
        const int base = lane * COLB;
#pragma unroll
        for (int m = 0; m < 6; ++m) {   // rows 4m..4m+3 (row 23 pads to 0)
            v2f wiA = L0WI[2 * m], wiB = L0WI[2 * m + 1];
            v2f uA  = __builtin_elementwise_fma(L0WS[2 * m],     Sv, L0BB[2 * m]);
            v2f uB  = __builtin_elementwise_fma(L0WS[2 * m + 1], Sv, L0BB[2 * m + 1]);
            v2f a0 = __builtin_elementwise_max(__builtin_elementwise_fma(wiA, lav, uA), z2);
            v2f b0 = __builtin_elementwise_max(__builtin_elementwise_fma(wiB, lav, uB), z2);
            v2f a1 = __builtin_elementwise_max(__builtin_elementwise_fma(wiA, lbv, uA), z2);
            v2f b1 = __builtin_elementwise_max(__builtin_elementwise_fma(wiB, lbv, uB), z2);
            v2f a2 = __builtin_elementwise_max(__builtin_elementwise_fma(wiA, lcv, uA), z2);
            v2f b2 = __builtin_elementwise_max(__builtin_elementwise_fma(wiB, lcv, uB), z2);
            int cb = base + (m >> 1) * 48 + (m & 1) * 8;
            *(f16x4*)(lds + cb +  0) = (f16x4){(_Float16)a0.x, (_Float16)a0.y, (_Float16)b0.x, (_Float16)b0.y};
            *(f16x4*)(lds + cb + 16) = (f16x4){(_Float16)a1.x, (_Float16)a1.y, (_Float16)b1.x, (_Float16)b1.y};
            *(f16x4*)(lds + cb + 32) = (f16x4){(_Float16)a2.x, (_Float16)a2.y, (_Float16)b2.x, (_Float16)b2.y};
        }
    }

    // layer-3 A fragment (4 VGPRs, loop-invariant)
    const f16x8 A3 = *(const f16x8*)(&g_a3frag[lane][0]);

    float eva = 0.0f, evb = 0.0f, evc = 0.0f;
    const f32x4 z4 = {0.f, 0.f, 0.f, 0.f};

    // ---- middle layers + fused layer 3, all on the matrix pipe ----
#pragma unroll
    for (int L = 0; L < 2; ++L) {
        f16x8 WiM0 = *(const f16x8*)(&g_afrag[L][0][0][lane][0]);
        f16x8 WiM1 = *(const f16x8*)(&g_afrag[L][0][1][lane][0]);
        f16x8 WsM0 = *(const f16x8*)(&g_afrag[L][1][0][lane][0]);
        f16x8 WsM1 = *(const f16x8*)(&g_afrag[L][1][1][lane][0]);
        const float* bb = L ? bb2 : bb1;
        f32x4 bvec[2];
#pragma unroll
        for (int mt = 0; mt < 2; ++mt)
#pragma unroll
            for (int rr = 0; rr < 4; ++rr) {
                int row = mt * 16 + 4 * g + rr;
                bvec[mt][rr] = (row < MLP_W) ? bb[row] : 0.0f;
            }

#pragma unroll
        for (int pp = 0; pp < 4; ++pp) {          // col-tiles (16 cols each)
            const int colb = (16 * pp + c16) * COLB;
            f16x8 bf[3];
#pragma unroll
            for (int h = 0; h < 3; ++h) {
                int off = (g == 3) ? ZOFF : (colb + g * 48 + h * 16);
                bf[h] = *(const f16x8*)(lds + off);   // one ds_read_b128
            }
            // id path: 6 independent MFMAs
            f32x4 c0m0 = mm16(WiM0, bf[0]);
            f32x4 c0m1 = mm16(WiM1, bf[0]);
            f32x4 c1m0 = mm16(WiM0, bf[1]);
            f32x4 c1m1 = mm16(WiM1, bf[1]);
            f32x4 c2m0 = mm16(WiM0, bf[2]);
            f32x4 c2m1 = mm16(WiM1, bf[2]);
            // sum path: Ws*(t0+t1+t2) via chained accumulate (f32)
            f32x4 sm0 = mm16a(WsM0, bf[2], mm16a(WsM0, bf[1], mm16(WsM0, bf[0])));
            f32x4 sm1 = mm16a(WsM1, bf[2], mm16a(WsM1, bf[1], mm16(WsM1, bf[0])));

            // packed epilogue: u = s + bias; y_d = relu(c_d + u); write back
#pragma unroll
            for (int mt = 0; mt < 2; ++mt) {
                if (mt == 1 && g >= 2) continue;  // rows 24..31 are pad
                f32x4 c0 = (mt == 0) ? c0m0 : c0m1;
                f32x4 c1 = (mt == 0) ? c1m0 : c1m1;
                f32x4 c2 = (mt == 0) ? c2m0 : c2m1;
                f32x4 cs = (mt == 0) ? sm0  : sm1;
                f32x4 u  = cs + bvec[mt];
                f32x4 y0 = __builtin_elementwise_max(c0 + u, z4);
                f32x4 y1 = __builtin_elementwise_max(c1 + u, z4);
                f32x4 y2 = __builtin_elementwise_max(c2 + u, z4);
                // rows 16mt+4g..+3 -> chunk 2mt+(g>>1), half (g&1)
                int wb = colb + (2 * mt + (g >> 1)) * 48 + (g & 1) * 8;
                *(f16x4*)(lds + wb +  0) = (f16x4){(_Float16)y0[0], (_Float16)y0[1], (_Float16)y0[2], (_Float16)y0[3]};
                *(f16x4*)(lds + wb + 16) = (f16x4){(_Float16)y1[0], (_Float16)y1[1], (_Float16)y1[2], (_Float16)y1[3]};
                *(f16x4*)(lds + wb + 32) = (f16x4){(_Float16)y2[0], (_Float16)y2[1], (_Float16)y2[2], (_Float16)y2[3]};
            }

            // fused layer 3 (after last middle layer): read fresh columns back
            // (same-wave DS => ordered), one MFMA per channel.
            if (L == 1) {
                f16x8 b2f[3];
#pragma unroll
                for (int h = 0; h < 3; ++h) {
                    int off = (g == 3) ? ZOFF : (colb + g * 48 + h * 16);
                    b2f[h] = *(const f16x8*)(lds + off);
                }
                f32x4 D0 = mm16(A3, b2f[0]);   // row0: dot(wi3,t0); row1: dot(ws3,t0)
                f32x4 D1 = mm16(A3, b2f[1]);
                f32x4 D2 = mm16(A3, b2f[2]);
                float ssum = D0[1] + D1[1] + D2[1];
                float ea = D0[0] + ssum;
                float eb = D1[0] + ssum;
                float ec = D2[0] + ssum;
                ea = __shfl(ea, c16);          // broadcast from g==0 lane of this col
                eb = __shfl(eb, c16);
                ec = __shfl(ec, c16);
                bool own = (g == pp);          // tile pp holds col == lane for g==pp
                eva = own ? ea : eva;
                evb = own ? eb : evb;
                evc = own ? ec : evc;
            }
        }
    }

    {
        float b3v = bb3[0];
        eva += b3v; evb += b3v; evc += b3v;
    }

    // ---- spectral reconstruction via Newton divided differences ----
    float g1 = (evb - eva) * sinv(lb - la);
    float g2 = (evc - evb) * sinv(lc - lb);
    float c2 = (g2 - g1) * sinv(lc - la);

    float m100 = x00 - la, m111 = x11 - la, m122 = x22 - la;
    float m200 = x00 - lb, m211 = x11 - lb, m222 = x22 - lb;

    float P00 = m100 * m200 + x01 * x01 + x02 * x02;
    float P01 = m100 * x01 + x01 * m211 + x02 * x12;
    float P02 = m100 * x02 + x01 * x12 + x02 * m222;
    float P11 = x01 * x01 + m111 * m211 + x12 * x12;
    float P12 = x01 * x02 + m111 * x12 + x12 * m222;
    float P22 = x02 * x02 + x12 * x12 + m122 * m222;

    float o00 = fmaf(g1, m100, eva) + c2 * P00;
    float o01 = g1 * x01 + c2 * P01;
    float o02 = g1 * x02 + c2 * P02;
    float o11 = fmaf(g1, m111, eva) + c2 * P11;
    float o12 = g1 * x12 + c2 * P12;
    float o22 = fmaf(g1, m122, eva) + c2 * P22;

    if (idx < B) {
        float* op = out + (size_t)idx * 9;
        op[0] = o00; op[1] = o01; op[2] = o02;
        op[3] = o01; op[4] = o11; op[5] = o12;
        op[6] = o02; op[7] = o12; op[8] = o22;
    }
}

extern "C" void kernel_launch(void* const* d_in, const int* in_sizes, int n_in,
                              void* d_out, int out_size, void* d_ws, size_t ws_size,
                              hipStream_t stream) {
    const float* x   = (const float*)d_in[0];
    const float* wi0 = (const float*)d_in[1];
    const float* ws0 = (const float*)d_in[2];
    const float* b0  = (const float*)d_in[3];
    const float* wi1 = (const float*)d_in[4];
    const float* ws1 = (const float*)d_in[5];
    const float* b1  = (const float*)d_in[6];
    const float* wi2 = (const float*)d_in[7];
    const float* ws2 = (const float*)d_in[8];
    const float* b2  = (const float*)d_in[9];
    const float* wi3 = (const float*)d_in[10];
    const float* ws3 = (const float*)d_in[11];
    const float* b3  = (const float*)d_in[12];

    int B = in_sizes[0] / 9;
    float* out = (float*)d_out;

    {
        dim3 block(256);
        dim3 grid(2);   // 512 threads cover afrag; subsets pack a3frag + l0
        hipLaunchKernelGGL(svh_prep_kernel, grid, block, 0, stream,
                           wi0, ws0, b0, wi1, ws1, wi2, ws2, wi3, ws3);
    }

    dim3 block(64);
    dim3 grid((B + 63) / 64);
    hipLaunchKernelGGL(svh_eig_mlp_kernel, grid, block, 0, stream,
                       x, b1, b2, b3, out, B);
}